// Round 7
// baseline (88.078 us; speedup 1.0000x reference)
//
#include <hip/hip_runtime.h>

// input_: (B=64, 2*N=16384, 2, 2, 16) f32 ; diag1/2: (N=8192, 2, 2, 8) f32
// out: (B, N, 2, 2, 23) f32
//   out[b,n,i,j,:] = sum_k conv(x1[b,n,i,k,:], d1[n,k,j,:]) + (x2, d2)
//
// Round 7: occupancy push. Round 6 (32 KB LDS, ~5 blocks/CU) hit 88 us vs
// ~70 us roofline; rounds 2-5 proved BW ~ resident waves. This round:
//   - 16 KB LDS: one x-buffer reused x1 -> x2 -> output (two 32-unit passes)
//     -> LDS allows 8 blocks/CU.
//   - live set squeezed to acc(23)+d(8)+one float4 of x+addr ~= 50 regs by
//     consuming x one ds_read_b128 at a time -> target VGPR <= 64 (the m69
//     occupancy cliff: 8 waves/SIMD at <=64). NO launch_bounds min-waves hint
//     (rounds 3/5: it makes the allocator spill catastrophically).
//   - XOR chunk swizzle (involution L = G ^ ((G>>3)&7)) on the x tile: the
//     compute read pattern (32 distinct chunks at stride 16, mod 8 == const)
//     is an 8-way bank-group conflict unswizzled.
#define BB 64
#define NN 8192
#define TILE 64
#define DOUT 23

__device__ __forceinline__ void compute_half(const float4* __restrict__ sbuf,
                                             const float4* __restrict__ dp,
                                             int unit, int i, float acc[DOUT]) {
#pragma unroll
    for (int k = 0; k < 2; ++k) {
        // d[n][k][j][v]: 8 floats (this thread's j baked into dp)
        float4 dq0 = dp[k * 4 + 0];
        float4 dq1 = dp[k * 4 + 1];
        const float dv[8] = {dq0.x, dq0.y, dq0.z, dq0.w,
                             dq1.x, dq1.y, dq1.z, dq1.w};
#pragma unroll
        for (int q = 0; q < 4; ++q) {
            const int G = unit * 16 + i * 8 + k * 4 + q;
            float4 xq = sbuf[G ^ ((G >> 3) & 7)];
            const float xe[4] = {xq.x, xq.y, xq.z, xq.w};
#pragma unroll
            for (int e = 0; e < 4; ++e) {
#pragma unroll
                for (int v = 0; v < 8; ++v) {
                    acc[q * 4 + e + v] += xe[e] * dv[v];  // u = q*4+e
                }
            }
        }
    }
}

__global__ __launch_bounds__(256) void hstackdiag_kernel(
    const float* __restrict__ input,
    const float* __restrict__ diag1,
    const float* __restrict__ diag2,
    float* __restrict__ out) {
    __shared__ float4 sbuf[1024];  // 16 KB, reused: x1 -> x2 -> output tile

    const int t = threadIdx.x;
    const int bx = blockIdx.x;
    const int b = bx >> 7;               // 128 ntiles per b
    const int n0 = (bx & 127) * TILE;

    // x tile (one half): 64 units x 64 floats = 1024 contiguous float4
    const float4* g1 = (const float4*)input + ((size_t)b * (2 * NN) + n0) * 16;
    const float4* g2 = g1 + (size_t)NN * 16;

    const int j = t & 1;
    const int i = (t >> 1) & 1;
    const int unit = t >> 2;
    const int n = n0 + unit;
    // d[n][k][j][v]: float4 index n*8 + k*4 + j*2
    const float4* dp1 = (const float4*)diag1 + (size_t)n * 8 + j * 2;
    const float4* dp2 = (const float4*)diag2 + (size_t)n * 8 + j * 2;

    float acc[DOUT];
#pragma unroll
    for (int u = 0; u < DOUT; ++u) acc[u] = 0.0f;

    // ---- stage x1 (4 coalesced float4 loads/thread, swizzled ds_write) ----
    {
        float4 r[4];
#pragma unroll
        for (int rr = 0; rr < 4; ++rr) r[rr] = g1[rr * 256 + t];
#pragma unroll
        for (int rr = 0; rr < 4; ++rr) {
            const int G = rr * 256 + t;
            sbuf[G ^ ((G >> 3) & 7)] = r[rr];
        }
    }
    __syncthreads();

    compute_half(sbuf, dp1, unit, i, acc);   // half 1

    __syncthreads();  // all waves done reading x1

    // ---- stage x2 into the same buffer ----
    {
        float4 r[4];
#pragma unroll
        for (int rr = 0; rr < 4; ++rr) r[rr] = g2[rr * 256 + t];
#pragma unroll
        for (int rr = 0; rr < 4; ++rr) {
            const int G = rr * 256 + t;
            sbuf[G ^ ((G >> 3) & 7)] = r[rr];
        }
    }
    __syncthreads();

    compute_half(sbuf, dp2, unit, i, acc);   // half 2

    __syncthreads();  // all waves done reading x2; reuse sbuf for output

    // ---- output: two passes of 32 units (11776 B) through LDS, then
    //      fully-coalesced contiguous stores ----
    float* sout = (float*)sbuf;
    const int c = i * 2 + j;
    float* gout = out + ((size_t)b * NN + n0) * (4 * DOUT);  // 23552 contiguous

#pragma unroll
    for (int p = 0; p < 2; ++p) {
        if ((unit >> 5) == p) {
#pragma unroll
            for (int q = 0; q < DOUT; ++q)
                sout[(unit & 31) * 92 + c * DOUT + q] = acc[q];
        }
        __syncthreads();
        // 32 units * 92 = 2944 floats = 11*256 + 128
#pragma unroll
        for (int rr = 0; rr < 11; ++rr)
            gout[p * 2944 + rr * 256 + t] = sout[rr * 256 + t];
        if (t < 128) gout[p * 2944 + 2816 + t] = sout[2816 + t];
        if (p == 0) __syncthreads();  // stores read sout before pass-1 writes
    }
}

extern "C" void kernel_launch(void* const* d_in, const int* in_sizes, int n_in,
                              void* d_out, int out_size, void* d_ws, size_t ws_size,
                              hipStream_t stream) {
    const float* input = (const float*)d_in[0];
    const float* diag1 = (const float*)d_in[1];
    const float* diag2 = (const float*)d_in[2];
    float* out = (float*)d_out;

    const int grid = BB * (NN / TILE);   // 64 * 128 = 8192 blocks
    hstackdiag_kernel<<<grid, 256, 0, stream>>>(input, diag1, diag2, out);
}